// Round 1
// baseline (593.861 us; speedup 1.0000x reference)
//
#include <hip/hip_runtime.h>
#include <hip/hip_bf16.h>

#define B_ 4096
#define L_ 200
#define D_ 64
#define NJ 36
#define H1 80
#define H2 40
#define GRID1 512
#define GB (B_/GRID1)
#define EPS_ 1e-8f

__device__ __forceinline__ float sigmoidf_(float x) { return 1.0f / (1.0f + __expf(-x)); }

// K0: build per-b folded AU weights WbT[b][j][d] = (W1a+W1c)[d][j] + it[b][d]*W1d[d][j]
//     and C[b][j] = it[b]·(W1b-W1c)[:,j] + au_b1[j]
__global__ void k_wb(const int* __restrict__ item, const float* __restrict__ i_emb,
                     const float* __restrict__ auW1, const float* __restrict__ aub1,
                     float* __restrict__ wbAll, float* __restrict__ cAll) {
    int b = blockIdx.x;
    __shared__ float it_s[D_];
    int tid = threadIdx.x;
    if (tid < D_) it_s[tid] = i_emb[(long)item[b] * D_ + tid];
    __syncthreads();
    if (tid < NJ) {
        float t = aub1[tid];
        for (int d = 0; d < D_; ++d)
            t += it_s[d] * (auW1[(64 + d) * NJ + tid] - auW1[(128 + d) * NJ + tid]);
        cAll[b * NJ + tid] = t;
    }
    for (int idx = tid; idx < NJ * D_; idx += blockDim.x) {
        int j = idx >> 6, d = idx & 63;
        wbAll[(long)b * NJ * D_ + idx] =
            auW1[d * NJ + j] + auW1[(128 + d) * NJ + j] + it_s[d] * auW1[(192 + d) * NJ + j];
    }
}

// K1: AU pass 1 — compute A[l,b,j] on the fly, accumulate per-block (sum, sumsq) over b in LDS,
//     write per-block partials to global (no contended atomics).
__global__ __launch_bounds__(256) void k_pass1(const int* __restrict__ hist,
        const float* __restrict__ i_emb, const float* __restrict__ wbAll,
        const float* __restrict__ cAll, float* __restrict__ partial) {
    __shared__ float sums[L_][NJ + 1];
    __shared__ float sqs[L_][NJ + 1];
    int l = threadIdx.x;
    if (l < L_) {
        #pragma unroll
        for (int j = 0; j < NJ; ++j) { sums[l][j] = 0.f; sqs[l][j] = 0.f; }
        for (int g = 0; g < GB; ++g) {
            int b = blockIdx.x * GB + g;
            int row = hist[l * B_ + b];
            const float4* hp = (const float4*)(i_emb + (long)row * D_);
            float4 h4[16];
            #pragma unroll
            for (int i = 0; i < 16; ++i) h4[i] = hp[i];
            const float4* wb = (const float4*)(wbAll + (long)b * NJ * D_);  // block-uniform -> s_load
            const float* cb = cAll + b * NJ;
            #pragma unroll 4
            for (int j = 0; j < NJ; ++j) {
                float s = cb[j];
                #pragma unroll
                for (int i = 0; i < 16; ++i) {
                    float4 w4 = wb[j * 16 + i];
                    s += h4[i].x * w4.x + h4[i].y * w4.y + h4[i].z * w4.z + h4[i].w * w4.w;
                }
                sums[l][j] += s; sqs[l][j] += s * s;
            }
        }
        float* po = partial + (long)blockIdx.x * (2 * L_ * NJ);
        #pragma unroll
        for (int j = 0; j < NJ; ++j) {
            po[l * NJ + j] = sums[l][j];
            po[L_ * NJ + l * NJ + j] = sqs[l][j];
        }
    }
}

// K1b: reduce partials -> mean, rstd per (l, j)
__global__ void k_stats_au(const float* __restrict__ partial,
                           float* __restrict__ meanA, float* __restrict__ rstdA) {
    int idx = blockIdx.x * blockDim.x + threadIdx.x;
    if (idx >= L_ * NJ) return;
    float s = 0.f, q = 0.f;
    for (int blk = 0; blk < GRID1; ++blk) {
        s += partial[(long)blk * (2 * L_ * NJ) + idx];
        q += partial[(long)blk * (2 * L_ * NJ) + L_ * NJ + idx];
    }
    float m = s * (1.0f / B_);
    float v = fmaxf(q * (1.0f / B_) - m * m, 0.f);
    meanA[idx] = m;
    rstdA[idx] = rsqrtf(v + EPS_);
}

// K2: AU pass 2 — recompute A, apply dice, w[l] = act·au_W2 + b2; fused weighted pooling
//     cur[d] = sum_l w[l]*h[l][d] via LDS transpose; also build z = [u | it | c | cur].
__global__ __launch_bounds__(256) void k_pass2(const int* __restrict__ hist,
        const int* __restrict__ user, const int* __restrict__ item, const int* __restrict__ cate,
        const float* __restrict__ u_emb, const float* __restrict__ i_emb, const float* __restrict__ c_emb,
        const float* __restrict__ wbAll, const float* __restrict__ cAll,
        const float* __restrict__ meanA, const float* __restrict__ rstdA,
        const float* __restrict__ alpha, const float* __restrict__ auW2, const float* __restrict__ aub2,
        float* __restrict__ z_buf) {
    __shared__ float tile[4][64][68];
    __shared__ float colsum[4][64];
    int b = blockIdx.x;
    int tid = threadIdx.x;
    int l = tid, wv = tid >> 6, ln = tid & 63;
    float4 h4[16];
    #pragma unroll
    for (int i = 0; i < 16; ++i) h4[i] = make_float4(0.f, 0.f, 0.f, 0.f);
    float w = 0.f;
    if (l < L_) {
        int row = hist[l * B_ + b];
        const float4* hp = (const float4*)(i_emb + (long)row * D_);
        #pragma unroll
        for (int i = 0; i < 16; ++i) h4[i] = hp[i];
        const float4* wb = (const float4*)(wbAll + (long)b * NJ * D_);
        const float* cb = cAll + b * NJ;
        w = aub2[0];
        #pragma unroll 4
        for (int j = 0; j < NJ; ++j) {
            float s = cb[j];
            #pragma unroll
            for (int i = 0; i < 16; ++i) {
                float4 w4 = wb[j * 16 + i];
                s += h4[i].x * w4.x + h4[i].y * w4.y + h4[i].z * w4.z + h4[i].w * w4.w;
            }
            float p = sigmoidf_((s - meanA[l * NJ + j]) * rstdA[l * NJ + j]);
            float a = s * (p + alpha[j] * (1.f - p));
            w += a * auW2[j];
        }
    }
    #pragma unroll
    for (int i = 0; i < 16; ++i) {
        float4 t = make_float4(w * h4[i].x, w * h4[i].y, w * h4[i].z, w * h4[i].w);
        *((float4*)&tile[wv][ln][i * 4]) = t;
    }
    __syncthreads();
    {
        int d = ln;
        float s = 0.f;
        #pragma unroll 8
        for (int ll = 0; ll < 64; ++ll) s += tile[wv][ll][d];
        colsum[wv][d] = s;
    }
    __syncthreads();
    if (tid < D_) {
        int d = tid;
        float cur = colsum[0][d] + colsum[1][d] + colsum[2][d] + colsum[3][d];
        z_buf[b * 256 + d]        = u_emb[(long)user[b] * D_ + d];
        z_buf[b * 256 + 64 + d]   = i_emb[(long)item[b] * D_ + d];
        z_buf[b * 256 + 128 + d]  = c_emb[(long)cate[b] * D_ + d];
        z_buf[b * 256 + 192 + d]  = cur;
    }
}

// K4: y1 = z @ W1 + b1, plus batch stats for dice1 (LDS partials + few global atomics)
__global__ __launch_bounds__(256) void k_mlp1(const float* __restrict__ z_buf,
        const float* __restrict__ W1, const float* __restrict__ b1,
        float* __restrict__ y1, float* __restrict__ gs1, float* __restrict__ gq1) {
    __shared__ float zt[16 * 256];
    __shared__ float w_s[256 * H1];
    __shared__ float ls[H1], lq[H1];
    int tid = threadIdx.x;
    int b0 = blockIdx.x * 16;
    for (int i = tid; i < 16 * 256; i += 256) zt[i] = z_buf[b0 * 256 + i];
    for (int i = tid; i < 256 * H1; i += 256) w_s[i] = W1[i];
    if (tid < H1) { ls[tid] = 0.f; lq[tid] = 0.f; }
    __syncthreads();
    for (int o = tid; o < 16 * H1; o += 256) {
        int bl = o / H1, j = o - bl * H1;
        float s = b1[j];
        for (int k = 0; k < 256; ++k) s += zt[bl * 256 + k] * w_s[k * H1 + j];
        y1[(b0 + bl) * H1 + j] = s;
        atomicAdd(&ls[j], s); atomicAdd(&lq[j], s * s);
    }
    __syncthreads();
    if (tid < H1) { atomicAdd(&gs1[tid], ls[tid]); atomicAdd(&gq1[tid], lq[tid]); }
}

__global__ void k_fin(const float* __restrict__ gs, const float* __restrict__ gq,
                      float* __restrict__ m, float* __restrict__ r, int n) {
    int i = blockIdx.x * blockDim.x + threadIdx.x;
    if (i < n) {
        float mm = gs[i] * (1.0f / B_);
        float v = fmaxf(gq[i] * (1.0f / B_) - mm * mm, 0.f);
        m[i] = mm; r[i] = rsqrtf(v + EPS_);
    }
}

// K6: a1 = dice1(y1); y2 = a1 @ W2 + b2, plus batch stats for dice2
__global__ __launch_bounds__(256) void k_mlp2(const float* __restrict__ y1,
        const float* __restrict__ m1, const float* __restrict__ r1, const float* __restrict__ alpha1,
        const float* __restrict__ W2, const float* __restrict__ b2,
        float* __restrict__ y2, float* __restrict__ gs2, float* __restrict__ gq2) {
    __shared__ float at[16 * H1];
    __shared__ float w_s[H1 * H2];
    __shared__ float ls[H2], lq[H2];
    int tid = threadIdx.x;
    int b0 = blockIdx.x * 16;
    for (int i = tid; i < 16 * H1; i += 256) {
        float x = y1[b0 * H1 + i];
        int j = i % H1;
        float p = sigmoidf_((x - m1[j]) * r1[j]);
        at[i] = x * (p + alpha1[j] * (1.f - p));
    }
    for (int i = tid; i < H1 * H2; i += 256) w_s[i] = W2[i];
    if (tid < H2) { ls[tid] = 0.f; lq[tid] = 0.f; }
    __syncthreads();
    for (int o = tid; o < 16 * H2; o += 256) {
        int bl = o / H2, j = o - bl * H2;
        float s = b2[j];
        #pragma unroll
        for (int k = 0; k < H1; ++k) s += at[bl * H1 + k] * w_s[k * H2 + j];
        y2[(b0 + bl) * H2 + j] = s;
        atomicAdd(&ls[j], s); atomicAdd(&lq[j], s * s);
    }
    __syncthreads();
    if (tid < H2) { atomicAdd(&gs2[tid], ls[tid]); atomicAdd(&gq2[tid], lq[tid]); }
}

// K8: out = dice2(y2) @ W3 + b3
__global__ void k_out(const float* __restrict__ y2,
        const float* __restrict__ m2, const float* __restrict__ r2, const float* __restrict__ alpha2,
        const float* __restrict__ W3, const float* __restrict__ b3, float* __restrict__ out) {
    int b = blockIdx.x * blockDim.x + threadIdx.x;
    if (b >= B_) return;
    float s0 = b3[0], s1 = b3[1];
    #pragma unroll
    for (int k = 0; k < H2; ++k) {
        float x = y2[b * H2 + k];
        float p = sigmoidf_((x - m2[k]) * r2[k]);
        float a = x * (p + alpha2[k] * (1.f - p));
        s0 += a * W3[k * 2];
        s1 += a * W3[k * 2 + 1];
    }
    out[b * 2] = s0;
    out[b * 2 + 1] = s1;
}

extern "C" void kernel_launch(void* const* d_in, const int* in_sizes, int n_in,
                              void* d_out, int out_size, void* d_ws, size_t ws_size,
                              hipStream_t stream) {
    const int*   user  = (const int*)d_in[0];
    const int*   hist  = (const int*)d_in[1];
    const int*   item  = (const int*)d_in[2];
    const int*   cate  = (const int*)d_in[3];
    const float* u_emb = (const float*)d_in[4];
    const float* i_emb = (const float*)d_in[5];
    const float* c_emb = (const float*)d_in[6];
    const float* auW1  = (const float*)d_in[7];
    const float* aub1  = (const float*)d_in[8];
    const float* aual  = (const float*)d_in[9];
    const float* auW2  = (const float*)d_in[10];
    const float* aub2  = (const float*)d_in[11];
    const float* W1    = (const float*)d_in[12];
    const float* b1    = (const float*)d_in[13];
    const float* al1   = (const float*)d_in[14];
    const float* W2    = (const float*)d_in[15];
    const float* b2    = (const float*)d_in[16];
    const float* al2   = (const float*)d_in[17];
    const float* W3    = (const float*)d_in[18];
    const float* b3    = (const float*)d_in[19];

    float* ws = (float*)d_ws;
    size_t off = 0;
    float* partial = ws + off; off += (size_t)GRID1 * 2 * L_ * NJ; // 29.5 MB
    float* meanA   = ws + off; off += L_ * NJ;
    float* rstdA   = ws + off; off += L_ * NJ;
    float* gs1     = ws + off; off += H1;
    float* gq1     = ws + off; off += H1;
    float* gs2     = ws + off; off += H2;
    float* gq2     = ws + off; off += H2;
    float* m1      = ws + off; off += H1;
    float* r1      = ws + off; off += H1;
    float* m2      = ws + off; off += H2;
    float* r2      = ws + off; off += H2;
    float* wbAll   = ws + off; off += (size_t)B_ * NJ * D_;        // 37.75 MB
    float* cAll    = ws + off; off += (size_t)B_ * NJ;
    float* z_buf   = ws + off; off += (size_t)B_ * 256;
    float* y1      = ws + off; off += (size_t)B_ * H1;
    float* y2      = ws + off; off += (size_t)B_ * H2;

    // zero the atomic stat accumulators (gs1,gq1,gs2,gq2 are contiguous)
    hipMemsetAsync(gs1, 0, (2 * H1 + 2 * H2) * sizeof(float), stream);

    k_wb<<<B_, 256, 0, stream>>>(item, i_emb, auW1, aub1, wbAll, cAll);
    k_pass1<<<GRID1, 256, 0, stream>>>(hist, i_emb, wbAll, cAll, partial);
    k_stats_au<<<(L_ * NJ + 255) / 256, 256, 0, stream>>>(partial, meanA, rstdA);
    k_pass2<<<B_, 256, 0, stream>>>(hist, user, item, cate, u_emb, i_emb, c_emb,
                                    wbAll, cAll, meanA, rstdA, aual, auW2, aub2, z_buf);
    k_mlp1<<<B_ / 16, 256, 0, stream>>>(z_buf, W1, b1, y1, gs1, gq1);
    k_fin<<<1, 128, 0, stream>>>(gs1, gq1, m1, r1, H1);
    k_mlp2<<<B_ / 16, 256, 0, stream>>>(y1, m1, r1, al1, W2, b2, y2, gs2, gq2);
    k_fin<<<1, 64, 0, stream>>>(gs2, gq2, m2, r2, H2);
    k_out<<<B_ / 256, 256, 0, stream>>>(y2, m2, r2, al2, W3, b3, (float*)d_out);
}

// Round 2
// 314.430 us; speedup vs baseline: 1.8887x; 1.8887x over previous
//
#include <hip/hip_runtime.h>
#include <hip/hip_bf16.h>

#define B_ 4096
#define L_ 200
#define D_ 64
#define NJ 36
#define H1 80
#define H2 40
#define BCH 32            // b-chunks for the stats reduction
#define BPC (B_/BCH)      // 128 b per chunk
#define LJ (L_*NJ)        // 7200
#define EPS_ 1e-8f

__device__ __forceinline__ float sigmoidf_(float x) { return 1.0f / (1.0f + __expf(-x)); }

// K1: per-b block. Build wb[j][d] = (W1a+W1c)[d][j] + it[d]*W1d[d][j] and
//     c[j] = it·(W1b-W1c)[:,j] + b1[j] in LDS, then each thread l computes
//     A[b][l][j] = h·wb[j] + c[j] for all 36 j and stores (coalesced).
__global__ __launch_bounds__(256) void k_pass1(const int* __restrict__ hist,
        const int* __restrict__ item, const float* __restrict__ i_emb,
        const float* __restrict__ auW1, const float* __restrict__ aub1,
        float* __restrict__ A) {
    __shared__ float it_s[D_];
    __shared__ float wbs[NJ * D_];
    __shared__ float cs[NJ];
    int b = blockIdx.x;
    int tid = threadIdx.x;
    if (tid < D_) it_s[tid] = i_emb[(long)item[b] * D_ + tid];
    __syncthreads();
    for (int idx = tid; idx < NJ * D_; idx += 256) {
        int j = idx >> 6, d = idx & 63;
        wbs[idx] = auW1[d * NJ + j] + auW1[(128 + d) * NJ + j] + it_s[d] * auW1[(192 + d) * NJ + j];
    }
    if (tid < NJ) {
        float t = aub1[tid];
        for (int d = 0; d < D_; ++d)
            t += it_s[d] * (auW1[(64 + d) * NJ + tid] - auW1[(128 + d) * NJ + tid]);
        cs[tid] = t;
    }
    __syncthreads();
    int l = tid;
    if (l >= L_) return;
    int row = hist[l * B_ + b];
    const float4* hp = (const float4*)(i_emb + (long)row * D_);
    float4 h4[16];
    #pragma unroll
    for (int i = 0; i < 16; ++i) h4[i] = hp[i];
    float4* out = (float4*)(A + ((long)b * L_ + l) * NJ);
    const float4* wb4 = (const float4*)wbs;
    #pragma unroll
    for (int j0 = 0; j0 < NJ; j0 += 4) {
        float s0 = cs[j0], s1 = cs[j0 + 1], s2 = cs[j0 + 2], s3 = cs[j0 + 3];
        #pragma unroll
        for (int i = 0; i < 16; ++i) {
            float4 h = h4[i];
            float4 w0 = wb4[(j0 + 0) * 16 + i];
            float4 w1 = wb4[(j0 + 1) * 16 + i];
            float4 w2 = wb4[(j0 + 2) * 16 + i];
            float4 w3 = wb4[(j0 + 3) * 16 + i];
            s0 += h.x * w0.x + h.y * w0.y + h.z * w0.z + h.w * w0.w;
            s1 += h.x * w1.x + h.y * w1.y + h.z * w1.z + h.w * w1.w;
            s2 += h.x * w2.x + h.y * w2.y + h.z * w2.z + h.w * w2.w;
            s3 += h.x * w3.x + h.y * w3.y + h.z * w3.z + h.w * w3.w;
        }
        out[j0 >> 2] = make_float4(s0, s1, s2, s3);
    }
}

// K1b: partial stats — chunk c reduces b in [c*BPC, (c+1)*BPC) for each (l,j).
//      A[b*LJ + lj] reads are perfectly coalesced (lj = thread id).
__global__ __launch_bounds__(256) void k_stats_p(const float* __restrict__ A,
        float* __restrict__ sp, float* __restrict__ sq) {
    int lj = blockIdx.x * 256 + threadIdx.x;
    if (lj >= LJ) return;
    int c = blockIdx.y;
    float s = 0.f, q = 0.f;
    const float* base = A + (long)c * BPC * LJ + lj;
    #pragma unroll 4
    for (int b = 0; b < BPC; ++b) {
        float v = base[(long)b * LJ];
        s += v; q += v * v;
    }
    sp[c * LJ + lj] = s;
    sq[c * LJ + lj] = q;
}

// K1c: finish stats -> mean, rstd per (l,j)
__global__ void k_stats_fin(const float* __restrict__ sp, const float* __restrict__ sq,
                            float* __restrict__ meanA, float* __restrict__ rstdA) {
    int lj = blockIdx.x * 256 + threadIdx.x;
    if (lj >= LJ) return;
    float s = 0.f, q = 0.f;
    for (int c = 0; c < BCH; ++c) { s += sp[c * LJ + lj]; q += sq[c * LJ + lj]; }
    float m = s * (1.0f / B_);
    float v = fmaxf(q * (1.0f / B_) - m * m, 0.f);
    meanA[lj] = m;
    rstdA[lj] = rsqrtf(v + EPS_);
}

// K2: per-b block. Read A, dice -> w[l]; pool cur[d] = sum_l w[l]*h[l][d] with a
//     tiny LDS (rows + wl + partials); build z = [u | it | c | cur].
__global__ __launch_bounds__(256) void k_pass2(const int* __restrict__ hist,
        const int* __restrict__ user, const int* __restrict__ item, const int* __restrict__ cate,
        const float* __restrict__ u_emb, const float* __restrict__ i_emb, const float* __restrict__ c_emb,
        const float* __restrict__ A, const float* __restrict__ meanA, const float* __restrict__ rstdA,
        const float* __restrict__ alpha, const float* __restrict__ auW2, const float* __restrict__ aub2,
        float* __restrict__ z_buf) {
    __shared__ int rows[L_];
    __shared__ float wl[L_];
    __shared__ float part[4][D_];
    int b = blockIdx.x;
    int tid = threadIdx.x;
    if (tid < L_) rows[tid] = hist[tid * B_ + b];
    int l = tid;
    if (l < L_) {
        const float* Ab = A + ((long)b * L_ + l) * NJ;
        const float* mb = meanA + l * NJ;
        const float* rb = rstdA + l * NJ;
        float w = aub2[0];
        #pragma unroll
        for (int j = 0; j < NJ; ++j) {
            float s = Ab[j];
            float p = sigmoidf_((s - mb[j]) * rb[j]);
            w += s * (p + alpha[j] * (1.f - p)) * auW2[j];
        }
        wl[l] = w;
    }
    __syncthreads();
    {
        int q = tid >> 6, d = tid & 63;
        int l0 = q * 50, l1 = l0 + 50;
        float s = 0.f;
        #pragma unroll 5
        for (int ll = l0; ll < l1; ++ll)
            s += wl[ll] * i_emb[(long)rows[ll] * D_ + d];
        part[q][d] = s;
    }
    __syncthreads();
    if (tid < D_) {
        int d = tid;
        float cur = part[0][d] + part[1][d] + part[2][d] + part[3][d];
        z_buf[b * 256 + d]       = u_emb[(long)user[b] * D_ + d];
        z_buf[b * 256 + 64 + d]  = i_emb[(long)item[b] * D_ + d];
        z_buf[b * 256 + 128 + d] = c_emb[(long)cate[b] * D_ + d];
        z_buf[b * 256 + 192 + d] = cur;
    }
}

// K4: y1 = z @ W1 + b1, plus batch stats for dice1
__global__ __launch_bounds__(256) void k_mlp1(const float* __restrict__ z_buf,
        const float* __restrict__ W1, const float* __restrict__ b1,
        float* __restrict__ y1, float* __restrict__ gs1, float* __restrict__ gq1) {
    __shared__ float zt[16 * 256];
    __shared__ float w_s[256 * H1];
    __shared__ float ls[H1], lq[H1];
    int tid = threadIdx.x;
    int b0 = blockIdx.x * 16;
    for (int i = tid; i < 16 * 256; i += 256) zt[i] = z_buf[b0 * 256 + i];
    for (int i = tid; i < 256 * H1; i += 256) w_s[i] = W1[i];
    if (tid < H1) { ls[tid] = 0.f; lq[tid] = 0.f; }
    __syncthreads();
    for (int o = tid; o < 16 * H1; o += 256) {
        int bl = o / H1, j = o - bl * H1;
        float s = b1[j];
        for (int k = 0; k < 256; ++k) s += zt[bl * 256 + k] * w_s[k * H1 + j];
        y1[(b0 + bl) * H1 + j] = s;
        atomicAdd(&ls[j], s); atomicAdd(&lq[j], s * s);
    }
    __syncthreads();
    if (tid < H1) { atomicAdd(&gs1[tid], ls[tid]); atomicAdd(&gq1[tid], lq[tid]); }
}

__global__ void k_fin(const float* __restrict__ gs, const float* __restrict__ gq,
                      float* __restrict__ m, float* __restrict__ r, int n) {
    int i = blockIdx.x * blockDim.x + threadIdx.x;
    if (i < n) {
        float mm = gs[i] * (1.0f / B_);
        float v = fmaxf(gq[i] * (1.0f / B_) - mm * mm, 0.f);
        m[i] = mm; r[i] = rsqrtf(v + EPS_);
    }
}

// K6: a1 = dice1(y1); y2 = a1 @ W2 + b2, plus batch stats for dice2
__global__ __launch_bounds__(256) void k_mlp2(const float* __restrict__ y1,
        const float* __restrict__ m1, const float* __restrict__ r1, const float* __restrict__ alpha1,
        const float* __restrict__ W2, const float* __restrict__ b2,
        float* __restrict__ y2, float* __restrict__ gs2, float* __restrict__ gq2) {
    __shared__ float at[16 * H1];
    __shared__ float w_s[H1 * H2];
    __shared__ float ls[H2], lq[H2];
    int tid = threadIdx.x;
    int b0 = blockIdx.x * 16;
    for (int i = tid; i < 16 * H1; i += 256) {
        float x = y1[b0 * H1 + i];
        int j = i % H1;
        float p = sigmoidf_((x - m1[j]) * r1[j]);
        at[i] = x * (p + alpha1[j] * (1.f - p));
    }
    for (int i = tid; i < H1 * H2; i += 256) w_s[i] = W2[i];
    if (tid < H2) { ls[tid] = 0.f; lq[tid] = 0.f; }
    __syncthreads();
    for (int o = tid; o < 16 * H2; o += 256) {
        int bl = o / H2, j = o - bl * H2;
        float s = b2[j];
        #pragma unroll
        for (int k = 0; k < H1; ++k) s += at[bl * H1 + k] * w_s[k * H2 + j];
        y2[(b0 + bl) * H2 + j] = s;
        atomicAdd(&ls[j], s); atomicAdd(&lq[j], s * s);
    }
    __syncthreads();
    if (tid < H2) { atomicAdd(&gs2[tid], ls[tid]); atomicAdd(&gq2[tid], lq[tid]); }
}

// K8: out = dice2(y2) @ W3 + b3
__global__ void k_out(const float* __restrict__ y2,
        const float* __restrict__ m2, const float* __restrict__ r2, const float* __restrict__ alpha2,
        const float* __restrict__ W3, const float* __restrict__ b3, float* __restrict__ out) {
    int b = blockIdx.x * blockDim.x + threadIdx.x;
    if (b >= B_) return;
    float s0 = b3[0], s1 = b3[1];
    #pragma unroll
    for (int k = 0; k < H2; ++k) {
        float x = y2[b * H2 + k];
        float p = sigmoidf_((x - m2[k]) * r2[k]);
        float a = x * (p + alpha2[k] * (1.f - p));
        s0 += a * W3[k * 2];
        s1 += a * W3[k * 2 + 1];
    }
    out[b * 2] = s0;
    out[b * 2 + 1] = s1;
}

extern "C" void kernel_launch(void* const* d_in, const int* in_sizes, int n_in,
                              void* d_out, int out_size, void* d_ws, size_t ws_size,
                              hipStream_t stream) {
    const int*   user  = (const int*)d_in[0];
    const int*   hist  = (const int*)d_in[1];
    const int*   item  = (const int*)d_in[2];
    const int*   cate  = (const int*)d_in[3];
    const float* u_emb = (const float*)d_in[4];
    const float* i_emb = (const float*)d_in[5];
    const float* c_emb = (const float*)d_in[6];
    const float* auW1  = (const float*)d_in[7];
    const float* aub1  = (const float*)d_in[8];
    const float* aual  = (const float*)d_in[9];
    const float* auW2  = (const float*)d_in[10];
    const float* aub2  = (const float*)d_in[11];
    const float* W1    = (const float*)d_in[12];
    const float* b1    = (const float*)d_in[13];
    const float* al1   = (const float*)d_in[14];
    const float* W2    = (const float*)d_in[15];
    const float* b2    = (const float*)d_in[16];
    const float* al2   = (const float*)d_in[17];
    const float* W3    = (const float*)d_in[18];
    const float* b3    = (const float*)d_in[19];

    float* ws = (float*)d_ws;
    size_t off = 0;
    float* A     = ws + off; off += (size_t)B_ * L_ * NJ;   // 118 MB
    float* sp    = ws + off; off += (size_t)BCH * LJ;       // 0.92 MB
    float* sq    = ws + off; off += (size_t)BCH * LJ;       // 0.92 MB
    float* meanA = ws + off; off += LJ;
    float* rstdA = ws + off; off += LJ;
    float* gs1   = ws + off; off += H1;
    float* gq1   = ws + off; off += H1;
    float* gs2   = ws + off; off += H2;
    float* gq2   = ws + off; off += H2;
    float* m1    = ws + off; off += H1;
    float* r1    = ws + off; off += H1;
    float* m2    = ws + off; off += H2;
    float* r2    = ws + off; off += H2;
    float* z_buf = ws + off; off += (size_t)B_ * 256;
    float* y1    = ws + off; off += (size_t)B_ * H1;
    float* y2    = ws + off; off += (size_t)B_ * H2;

    hipMemsetAsync(gs1, 0, (2 * H1 + 2 * H2) * sizeof(float), stream);

    k_pass1<<<B_, 256, 0, stream>>>(hist, item, i_emb, auW1, aub1, A);
    {
        dim3 g((LJ + 255) / 256, BCH);
        k_stats_p<<<g, 256, 0, stream>>>(A, sp, sq);
    }
    k_stats_fin<<<(LJ + 255) / 256, 256, 0, stream>>>(sp, sq, meanA, rstdA);
    k_pass2<<<B_, 256, 0, stream>>>(hist, user, item, cate, u_emb, i_emb, c_emb,
                                    A, meanA, rstdA, aual, auW2, aub2, z_buf);
    k_mlp1<<<B_ / 16, 256, 0, stream>>>(z_buf, W1, b1, y1, gs1, gq1);
    k_fin<<<1, 128, 0, stream>>>(gs1, gq1, m1, r1, H1);
    k_mlp2<<<B_ / 16, 256, 0, stream>>>(y1, m1, r1, al1, W2, b2, y2, gs2, gq2);
    k_fin<<<1, 64, 0, stream>>>(gs2, gq2, m2, r2, H2);
    k_out<<<B_ / 256, 256, 0, stream>>>(y2, m2, r2, al2, W3, b3, (float*)d_out);
}